// Round 12
// baseline (193.362 us; speedup 1.0000x reference)
//
#include <hip/hip_runtime.h>
#include <hip/hip_bf16.h>
#include <stdint.h>

// Attention fwd: B=2, N=2048, D=768, H=12, Dh=64, INNER=768
// R12 = 3 LAUNCHES ONLY (launch-overhead hypothesis test; non-attn has been
// invariant ~120us across R2-R11 despite major gemm retiles):
//   gemm_qkv: reads x fp32 + w_qkv fp32 DIRECTLY (cvt + transpose in staging)
//   attn_k:   byte-identical R11 (55.2us measured control)
//   gemm_out: reads Ab bf16 (DMA) + w_out fp32 directly (transpose staging)
// Staging bank math: A short4 stores pad-40 = 2-way free; B transpose stores
// (kr=fi&31 mapping) = exact 2-way free; all frag reads 16B-aligned (pad 40).

typedef __attribute__((ext_vector_type(8))) short bf16x8;
typedef __attribute__((ext_vector_type(4))) float f32x4;
typedef __attribute__((address_space(3))) unsigned int lds_uint;
typedef __attribute__((address_space(1))) const unsigned int g_uint;

__device__ __forceinline__ short f2bf(float f) {
    union { float f; uint32_t u; } x; x.f = f;
    uint32_t r = (x.u + 0x7fffu + ((x.u >> 16) & 1u)) >> 16;
    return (short)r;
}
__device__ __forceinline__ uint32_t packbf(float a, float b) {
    union { float f; uint32_t u; } xa, xb; xa.f = a; xb.f = b;
    return __builtin_amdgcn_perm(xb.u + 0x8000u, xa.u + 0x8000u, 0x07060302u);
}
__device__ __forceinline__ float exp2fast(float x) {
#if __has_builtin(__builtin_amdgcn_exp2f)
    return __builtin_amdgcn_exp2f(x);
#else
    return __expf(x * 0.6931471805599453f);
#endif
}
__device__ __forceinline__ void gl_lds16(const void* g, void* l) {
    __builtin_amdgcn_global_load_lds((g_uint*)g, (lds_uint*)l, 16, 0, 0);
}

// ---------------------------------------------------------------------------
// QKV GEMM, fused prep: C[4096x2304] = x[4096x768]fp32 @ w_qkv[768x2304]fp32
// + b -> Qb(pre-scaled)/Kb/Vt bf16. 128x96 tiles, 768 blocks = 3/CU exact.
// A staged with inline fp32->bf16 (pad 40); B staged with inline transpose
// (W[k][n] -> Bs[n][k], pad 40, conflict-free store mapping kr=fi&31).
// Vt layout TILED: Vt[bh][kt][d][n&63] (64x64 tiles, 8KB, dense windows)
// ---------------------------------------------------------------------------
__global__ __launch_bounds__(256)
void gemm_qkv(const float* __restrict__ X, const float* __restrict__ Wq,
              const float* __restrict__ bias,
              short* __restrict__ Qb, short* __restrict__ Kb, short* __restrict__ Vt)
{
    __shared__ short As[128 * 40];
    __shared__ short Bs[96 * 40];
    const int tid = threadIdx.x, lane = tid & 63, w = tid >> 6;
    const int wm = w >> 1, wn = w & 1, quad = lane >> 4, lcol = lane & 15;
    const int bm = blockIdx.y * 128, bn = blockIdx.x * 96;

    f32x4 acc[4][3];
    #pragma unroll
    for (int i = 0; i < 4; i++)
        #pragma unroll
        for (int j = 0; j < 3; j++) acc[i][j] = (f32x4){0.f, 0.f, 0.f, 0.f};

    for (int kt = 0; kt < 768; kt += 32) {
        // ---- A: 128x32 fp32 -> bf16, 1024 float4, 4/thread ----
        #pragma unroll
        for (int i = 0; i < 4; i++) {
            int fi = tid + i * 256;
            int r = fi >> 3, c = (fi & 7) << 2;
            float4 f = *(const float4*)(X + (size_t)(bm + r) * 768 + kt + c);
            short4 s;
            s.x = f2bf(f.x); s.y = f2bf(f.y); s.z = f2bf(f.z); s.w = f2bf(f.w);
            *(short4*)(As + r * 40 + c) = s;
        }
        // ---- B: W[kt..+32][bn..+96] fp32 -> Bs[n][k] bf16 transposed ----
        // 768 float4, 3/thread; kr=fi&31 (low bits) => stores exactly 2-way
        #pragma unroll
        for (int j = 0; j < 3; j++) {
            int fi = tid + j * 256;
            int kr = fi & 31, ng = fi >> 5;       // ng: 0..23 (float4 col group)
            float4 f = *(const float4*)(Wq + (size_t)(kt + kr) * 2304 + bn + ng * 4);
            Bs[(ng * 4 + 0) * 40 + kr] = f2bf(f.x);
            Bs[(ng * 4 + 1) * 40 + kr] = f2bf(f.y);
            Bs[(ng * 4 + 2) * 40 + kr] = f2bf(f.z);
            Bs[(ng * 4 + 3) * 40 + kr] = f2bf(f.w);
        }
        __syncthreads();
        bf16x8 a[4], b[3];
        #pragma unroll
        for (int tm = 0; tm < 4; tm++)
            a[tm] = *(const bf16x8*)(As + (wm*64 + tm*16 + lcol) * 40 + quad * 8);
        #pragma unroll
        for (int tn = 0; tn < 3; tn++)
            b[tn] = *(const bf16x8*)(Bs + (wn*48 + tn*16 + lcol) * 40 + quad * 8);
        #pragma unroll
        for (int tm = 0; tm < 4; tm++)
            #pragma unroll
            for (int tn = 0; tn < 3; tn++)
                acc[tm][tn] = __builtin_amdgcn_mfma_f32_16x16x32_bf16(a[tm], b[tn], acc[tm][tn], 0, 0, 0);
        __syncthreads();
    }

    const float SCLQ = 0.18033688011112042f;   // 0.125 * log2(e) folded into Q
    #pragma unroll
    for (int tm = 0; tm < 4; tm++) {
        #pragma unroll
        for (int tn = 0; tn < 3; tn++) {
            int col = bn + wn*48 + tn*16 + lcol;
            float bv = bias[col];
            int which = (col >= 1536) ? 2 : (col >= 768 ? 1 : 0);
            int cc = col - which * 768;
            int h = cc >> 6, d = cc & 63;
            int rowbase = bm + wm*64 + tm*16 + quad*4;
            int bb = rowbase >> 11, n0 = rowbase & 2047;
            int bh = bb * 12 + h;
            if (which == 2) {                 // V: tiled V^T store, dense window
                short4 s4;
                s4.x = f2bf(acc[tm][tn][0] + bv);
                s4.y = f2bf(acc[tm][tn][1] + bv);
                s4.z = f2bf(acc[tm][tn][2] + bv);
                s4.w = f2bf(acc[tm][tn][3] + bv);
                *(short4*)(Vt + (((size_t)bh*32 + (n0 >> 6))*64 + d)*64 + (n0 & 63)) = s4;
            } else {
                #pragma unroll
                for (int reg = 0; reg < 4; reg++) {
                    float v = acc[tm][tn][reg] + bv;
                    if (which == 0) v *= SCLQ;
                    short* dst = (which == 0) ? Qb : Kb;
                    dst[((size_t)bh*2048 + n0 + reg)*64 + d] = f2bf(v);
                }
            }
        }
    }
}

// ---------------------------------------------------------------------------
// Flash attention — byte-identical R11 (55.2us measured).
// ---------------------------------------------------------------------------
__global__ __launch_bounds__(256)
void attn_k(const short* __restrict__ Q, const short* __restrict__ K,
            const short* __restrict__ Vt, short* __restrict__ Ab)
{
    __shared__ short Ks[2][4096];      // [kv][d] xor-swizzled chunks
    __shared__ short Vs[2][4096];      // [d][kv] xor-swizzled chunks
    __shared__ short Ps[64 * 72];      // shared P tile [q][kv], pad 72
    __shared__ float lsum[64];

    const int tid = threadIdx.x, lane = tid & 63, w = tid >> 6;
    const int quad = lane >> 4, lcol = lane & 15;
    const int bid = blockIdx.x;
    const int bh = bid % 24, qt = bid / 24;
    const int b = bh / 12, h = bh - b * 12;

    const short* Kg = K  + (size_t)bh * 131072;   // [n][d] rows, tile = 8KB
    const short* Vg = Vt + (size_t)bh * 131072;   // tiled [kt][d][n64], 8KB

    bf16x8 qf[4][2];
    {
        const short* Qg = Q + ((size_t)bh * 2048 + (size_t)qt * 64) * 64;
        #pragma unroll
        for (int qs = 0; qs < 4; qs++)
            #pragma unroll
            for (int ks = 0; ks < 2; ks++)
                qf[qs][ks] = *(const bf16x8*)(Qg + (qs*16 + lcol) * 64 + ks*32 + quad*8);
    }

    if (tid < 64) lsum[tid] = 0.f;
    #pragma unroll
    for (int i = 0; i < 2; i++) {
        int c = tid + i * 256, row = c >> 3, cs = c & 7, gc = cs ^ (row & 7);
        gl_lds16(Kg + row * 64 + gc * 8, Ks[0] + c * 8);
        gl_lds16(Vg + row * 64 + gc * 8, Vs[0] + c * 8);
    }
    __syncthreads();

    f32x4 o[4];
    #pragma unroll
    for (int tn = 0; tn < 4; tn++) o[tn] = (f32x4){0.f, 0.f, 0.f, 0.f};
    float lp[4] = {0.f, 0.f, 0.f, 0.f};

    const int krow = w * 16 + lcol;
    const int ksw  = krow & 7;

    for (int kt = 0; kt < 32; kt++) {
        const int p = kt & 1;
        if (kt < 31) {
            #pragma unroll
            for (int i = 0; i < 2; i++) {
                int c = tid + i * 256, row = c >> 3, cs = c & 7, gc = cs ^ (row & 7);
                gl_lds16(Kg + (kt + 1) * 4096 + row * 64 + gc * 8, Ks[p ^ 1] + c * 8);
                gl_lds16(Vg + (kt + 1) * 4096 + row * 64 + gc * 8, Vs[p ^ 1] + c * 8);
            }
        }

        f32x4 st[4];
        #pragma unroll
        for (int qs = 0; qs < 4; qs++) st[qs] = (f32x4){0.f, 0.f, 0.f, 0.f};
        #pragma unroll
        for (int ks = 0; ks < 2; ks++) {
            bf16x8 kf = *(const bf16x8*)(Ks[p] + krow * 64 + (((ks*4 + quad) ^ ksw) << 3));
            #pragma unroll
            for (int qs = 0; qs < 4; qs++)
                st[qs] = __builtin_amdgcn_mfma_f32_16x16x32_bf16(kf, qf[qs][ks], st[qs], 0, 0, 0);
        }

        #pragma unroll
        for (int qs = 0; qs < 4; qs++) {
            float p0 = exp2fast(st[qs][0]), p1 = exp2fast(st[qs][1]);
            float p2 = exp2fast(st[qs][2]), p3 = exp2fast(st[qs][3]);
            lp[qs] += (p0 + p1) + (p2 + p3);
            uint32_t uu[2] = { packbf(p0, p1), packbf(p2, p3) };
            *(uint32_t*)(Ps + (qs*16 + lcol) * 72 + w*16 + quad*4)     = uu[0];
            *(uint32_t*)(Ps + (qs*16 + lcol) * 72 + w*16 + quad*4 + 2) = uu[1];
        }
        __syncthreads();               // barrier 1: P visible + prefetch drained

        #pragma unroll
        for (int ks = 0; ks < 2; ks++) {
            bf16x8 ap = *(const bf16x8*)(Ps + (w*16 + lcol) * 72 + ks * 32 + quad * 8);
            #pragma unroll
            for (int tn = 0; tn < 4; tn++) {
                int row = tn * 16 + lcol;
                bf16x8 bv = *(const bf16x8*)(Vs[p] + row * 64 +
                                             (((ks * 4 + quad) ^ (row & 7)) << 3));
                o[tn] = __builtin_amdgcn_mfma_f32_16x16x32_bf16(ap, bv, o[tn], 0, 0, 0);
            }
        }
        __syncthreads();               // barrier 2: staging swap + Ps reuse
    }

    #pragma unroll
    for (int qs = 0; qs < 4; qs++) {
        float v = lp[qs];
        v += __shfl_xor(v, 16, 64);
        v += __shfl_xor(v, 32, 64);
        if (quad == 0) atomicAdd(&lsum[qs*16 + lcol], v);
    }
    __syncthreads();
    #pragma unroll
    for (int tn = 0; tn < 4; tn++) {
        #pragma unroll
        for (int r = 0; r < 4; r++) {
            int q = qt * 64 + w * 16 + quad * 4 + r;
            int d = h * 64 + tn * 16 + lcol;
            float rl = 1.0f / lsum[w * 16 + quad * 4 + r];
            Ab[((size_t)(b * 2048 + q)) * 768 + d] = f2bf(o[tn][r] * rl);
        }
    }
}

// ---------------------------------------------------------------------------
// out-proj GEMM, fused w_out transpose: out[4096x768]fp32 =
// Ab[4096x768]bf16 @ w_out[768x768]fp32 + b. 64x96 tiles, 512 blocks = 2/CU.
// A via gl_lds16 (unpadded 32); B via inline transpose staging (pad 40).
// ---------------------------------------------------------------------------
__global__ __launch_bounds__(256)
void gemm_out(const short* __restrict__ A, const float* __restrict__ Wo,
              const float* __restrict__ bias, float* __restrict__ Of)
{
    __shared__ short As[64 * 32];      // 256 chunks (DMA)
    __shared__ short Bs[96 * 40];
    const int tid = threadIdx.x, lane = tid & 63, w = tid >> 6;
    const int wm = w >> 1, wn = w & 1, quad = lane >> 4, lcol = lane & 15;
    const int bm = blockIdx.y * 64, bn = blockIdx.x * 96;

    f32x4 acc[2][3];
    #pragma unroll
    for (int i = 0; i < 2; i++)
        #pragma unroll
        for (int j = 0; j < 3; j++) acc[i][j] = (f32x4){0.f, 0.f, 0.f, 0.f};

    for (int kt = 0; kt < 768; kt += 32) {
        {
            int row = tid >> 2, cs = tid & 3;
            gl_lds16(A + (size_t)(bm + row) * 768 + kt + cs * 8, As + tid * 8);
        }
        #pragma unroll
        for (int j = 0; j < 3; j++) {
            int fi = tid + j * 256;
            int kr = fi & 31, ng = fi >> 5;
            float4 f = *(const float4*)(Wo + (size_t)(kt + kr) * 768 + bn + ng * 4);
            Bs[(ng * 4 + 0) * 40 + kr] = f2bf(f.x);
            Bs[(ng * 4 + 1) * 40 + kr] = f2bf(f.y);
            Bs[(ng * 4 + 2) * 40 + kr] = f2bf(f.z);
            Bs[(ng * 4 + 3) * 40 + kr] = f2bf(f.w);
        }
        __syncthreads();
        bf16x8 a[2], b[3];
        #pragma unroll
        for (int tm = 0; tm < 2; tm++)
            a[tm] = *(const bf16x8*)(As + (wm*32 + tm*16 + lcol) * 32 + quad * 8);
        #pragma unroll
        for (int tn = 0; tn < 3; tn++)
            b[tn] = *(const bf16x8*)(Bs + (wn*48 + tn*16 + lcol) * 40 + quad * 8);
        #pragma unroll
        for (int tm = 0; tm < 2; tm++)
            #pragma unroll
            for (int tn = 0; tn < 3; tn++)
                acc[tm][tn] = __builtin_amdgcn_mfma_f32_16x16x32_bf16(a[tm], b[tn], acc[tm][tn], 0, 0, 0);
        __syncthreads();
    }
    #pragma unroll
    for (int tm = 0; tm < 2; tm++) {
        #pragma unroll
        for (int tn = 0; tn < 3; tn++) {
            int col = bn + wn*48 + tn*16 + lcol;
            float bv = bias[col];
            #pragma unroll
            for (int reg = 0; reg < 4; reg++) {
                int row = bm + wm*32 + tm*16 + quad*4 + reg;
                Of[(size_t)row * 768 + col] = acc[tm][tn][reg] + bv;
            }
        }
    }
}

// ---------------------------------------------------------------------------
extern "C" void kernel_launch(void* const* d_in, const int* in_sizes, int n_in,
                              void* d_out, int out_size, void* d_ws, size_t ws_size,
                              hipStream_t stream)
{
    (void)in_sizes; (void)n_in; (void)out_size; (void)ws_size;
    const float* x     = (const float*)d_in[0];
    const float* w_qkv = (const float*)d_in[1];
    const float* b_qkv = (const float*)d_in[2];
    const float* w_out = (const float*)d_in[3];
    const float* b_out = (const float*)d_in[4];
    float* out = (float*)d_out;

    const size_t HSZ = (size_t)24 * 2048 * 64;   // bf16 elems per Q/K/V buffer
    short* Qb = (short*)d_ws;
    short* Kb = Qb + HSZ;
    short* Vt = Kb + HSZ;
    short* Ab = Vt + HSZ;                        // [4096][768] bf16

    gemm_qkv<<<dim3(24, 32), 256, 0, stream>>>(x, w_qkv, b_qkv, Qb, Kb, Vt);
    attn_k<<<768, 256, 0, stream>>>(Qb, Kb, Vt, Ab);
    gemm_out<<<dim3(8, 64), 256, 0, stream>>>(Ab, w_out, b_out, out);
}

// Round 13
// 164.303 us; speedup vs baseline: 1.1769x; 1.1769x over previous
//
#include <hip/hip_runtime.h>
#include <hip/hip_bf16.h>
#include <stdint.h>

// Attention fwd: B=2, N=2048, D=768, H=12, Dh=64, INNER=768
// R13 = R11 (best, 175.1us) + DOUBLE-BUFFERED DMA staging in both gemms
// (attn-proven: prefetch next tile into alt LDS buffer during compute,
//  1 barrier/iter instead of stage->barrier->compute->barrier).
// R12 post-mortem: direct measurement showed fused-fp32-staging gemm_qkv =
// 59us @ MfmaUtil 9% (VALU staging trap + 0-distance stage->consume stall);
// launch count is NOT the non-attn cost. attn_k byte-identical R11 control.

typedef __attribute__((ext_vector_type(8))) short bf16x8;
typedef __attribute__((ext_vector_type(4))) float f32x4;
typedef __attribute__((address_space(3))) unsigned int lds_uint;
typedef __attribute__((address_space(1))) const unsigned int g_uint;

__device__ __forceinline__ short f2bf(float f) {
    union { float f; uint32_t u; } x; x.f = f;
    uint32_t r = (x.u + 0x7fffu + ((x.u >> 16) & 1u)) >> 16;
    return (short)r;
}
__device__ __forceinline__ uint32_t packbf(float a, float b) {
    union { float f; uint32_t u; } xa, xb; xa.f = a; xb.f = b;
    return __builtin_amdgcn_perm(xb.u + 0x8000u, xa.u + 0x8000u, 0x07060302u);
}
__device__ __forceinline__ float exp2fast(float x) {
#if __has_builtin(__builtin_amdgcn_exp2f)
    return __builtin_amdgcn_exp2f(x);
#else
    return __expf(x * 0.6931471805599453f);
#endif
}
__device__ __forceinline__ void gl_lds16(const void* g, void* l) {
    __builtin_amdgcn_global_load_lds((g_uint*)g, (lds_uint*)l, 16, 0, 0);
}

// ---------------------------------------------------------------------------
// 64x64 fp32->bf16 transpose tile (shared by prep_k / tr_w)
// ---------------------------------------------------------------------------
__device__ __forceinline__ void tr_tile(const float* __restrict__ W,
                                        short* __restrict__ Wt, int K, int N,
                                        int n0, int k0, int t, short* S) {
    {
        int kl = t >> 2, ng = t & 3;
        const float* src = W + (size_t)(k0 + kl) * N + n0 + ng * 16;
        #pragma unroll
        for (int j = 0; j < 16; j += 4) {
            float4 f = *(const float4*)(src + j);
            S[(ng*16 + j + 0) * 65 + kl] = f2bf(f.x);
            S[(ng*16 + j + 1) * 65 + kl] = f2bf(f.y);
            S[(ng*16 + j + 2) * 65 + kl] = f2bf(f.z);
            S[(ng*16 + j + 3) * 65 + kl] = f2bf(f.w);
        }
    }
    __syncthreads();
    {
        int nl = t >> 2, kg = t & 3;
        short* dst = Wt + (size_t)(n0 + nl) * K + k0 + kg * 16;
        #pragma unroll
        for (int j = 0; j < 16; j += 4) {
            short4 s4;
            s4.x = S[nl*65 + kg*16 + j + 0];
            s4.y = S[nl*65 + kg*16 + j + 1];
            s4.z = S[nl*65 + kg*16 + j + 2];
            s4.w = S[nl*65 + kg*16 + j + 3];
            *(short4*)(dst + j) = s4;
        }
    }
}

// fused prep: [0,1536) x->bf16 ; [1536,1968) w_qkv^T ; [1968,2112) w_out^T
__global__ __launch_bounds__(256)
void prep_k(const float* __restrict__ x, short* __restrict__ Xb,
            const float* __restrict__ Wq, short* __restrict__ Wqt,
            const float* __restrict__ Wo, short* __restrict__ Wot)
{
    __shared__ short S[64 * 65];
    const int t = threadIdx.x;
    if (blockIdx.x < 1536) {
        int i = (blockIdx.x * 256 + t) * 8;
        float4 f0 = *(const float4*)(x + i);
        float4 f1 = *(const float4*)(x + i + 4);
        short s[8];
        s[0]=f2bf(f0.x); s[1]=f2bf(f0.y); s[2]=f2bf(f0.z); s[3]=f2bf(f0.w);
        s[4]=f2bf(f1.x); s[5]=f2bf(f1.y); s[6]=f2bf(f1.z); s[7]=f2bf(f1.w);
        *(uint4*)(Xb + i) = *(uint4*)s;
        return;
    }
    if (blockIdx.x < 1968) {
        const int b2 = blockIdx.x - 1536;                  // N=2304, K=768
        tr_tile(Wq, Wqt, 768, 2304, (b2 % 36) * 64, (b2 / 36) * 64, t, S);
    } else {
        const int b3 = blockIdx.x - 1968;                  // N=768, K=768
        tr_tile(Wo, Wot, 768, 768, (b3 % 12) * 64, (b3 / 12) * 64, t, S);
    }
}

// standalone w_out transpose (fallback when Wot must alias Wqt)
__global__ __launch_bounds__(256)
void tr_w(const float* __restrict__ W, short* __restrict__ Wt, int K, int N) {
    __shared__ short S[64 * 65];
    tr_tile(W, Wt, K, N, blockIdx.x * 64, blockIdx.y * 64, threadIdx.x, S);
}

// ---------------------------------------------------------------------------
// QKV GEMM R13: 128x96 tiles, 768 blocks = 3/CU, DOUBLE-BUFFERED DMA staging
// (prefetch kt+1 into alt buffer during compute on kt; 1 barrier/iter).
// [4096x768]bf16 @ Wqt[2304x768]^T + b -> Qb(pre-scaled)/Kb/Vt bf16
// Vt layout TILED: Vt[bh][kt][d][n&63] (64x64 tiles, 8KB, dense windows)
// ---------------------------------------------------------------------------
__global__ __launch_bounds__(256)
void gemm_qkv(const short* __restrict__ A, const short* __restrict__ Bt,
              const float* __restrict__ bias,
              short* __restrict__ Qb, short* __restrict__ Kb, short* __restrict__ Vt)
{
    __shared__ short As[2][128 * 32];  // 512 chunks of 16B each buffer
    __shared__ short Bs[2][96 * 32];   // 384 chunks
    const int tid = threadIdx.x, lane = tid & 63, w = tid >> 6;
    const int wm = w >> 1, wn = w & 1, quad = lane >> 4, lcol = lane & 15;
    const int bm = blockIdx.y * 128, bn = blockIdx.x * 96;

    f32x4 acc[4][3];
    #pragma unroll
    for (int i = 0; i < 4; i++)
        #pragma unroll
        for (int j = 0; j < 3; j++) acc[i][j] = (f32x4){0.f, 0.f, 0.f, 0.f};

    // stage tile 0 into buffer 0
    {
        #pragma unroll
        for (int i = 0; i < 2; i++) {
            int c = tid + i * 256, row = c >> 2, cs = c & 3;
            gl_lds16(A + (size_t)(bm + row) * 768 + cs * 8, As[0] + c * 8);
        }
        int c = tid, row = c >> 2, cs = c & 3;
        gl_lds16(Bt + (size_t)(bn + row) * 768 + cs * 8, Bs[0] + c * 8);
        if (tid < 128) {
            int c2 = 256 + tid, row2 = c2 >> 2, cs2 = c2 & 3;
            gl_lds16(Bt + (size_t)(bn + row2) * 768 + cs2 * 8, Bs[0] + c2 * 8);
        }
    }
    __syncthreads();

    for (int it = 0; it < 24; it++) {
        const int p = it & 1;
        if (it < 23) {                 // prefetch next k-tile into alt buffer
            int kt = (it + 1) * 32;
            #pragma unroll
            for (int i = 0; i < 2; i++) {
                int c = tid + i * 256, row = c >> 2, cs = c & 3;
                gl_lds16(A + (size_t)(bm + row) * 768 + kt + cs * 8, As[p ^ 1] + c * 8);
            }
            int c = tid, row = c >> 2, cs = c & 3;
            gl_lds16(Bt + (size_t)(bn + row) * 768 + kt + cs * 8, Bs[p ^ 1] + c * 8);
            if (tid < 128) {
                int c2 = 256 + tid, row2 = c2 >> 2, cs2 = c2 & 3;
                gl_lds16(Bt + (size_t)(bn + row2) * 768 + kt + cs2 * 8, Bs[p ^ 1] + c2 * 8);
            }
        }
        bf16x8 a[4], b[3];
        #pragma unroll
        for (int tm = 0; tm < 4; tm++)
            a[tm] = *(const bf16x8*)(As[p] + (wm*64 + tm*16 + lcol) * 32 + quad * 8);
        #pragma unroll
        for (int tn = 0; tn < 3; tn++)
            b[tn] = *(const bf16x8*)(Bs[p] + (wn*48 + tn*16 + lcol) * 32 + quad * 8);
        #pragma unroll
        for (int tm = 0; tm < 4; tm++)
            #pragma unroll
            for (int tn = 0; tn < 3; tn++)
                acc[tm][tn] = __builtin_amdgcn_mfma_f32_16x16x32_bf16(a[tm], b[tn], acc[tm][tn], 0, 0, 0);
        __syncthreads();               // drains prefetch DMA + guards buffer swap
    }

    const float SCLQ = 0.18033688011112042f;   // 0.125 * log2(e) folded into Q
    #pragma unroll
    for (int tm = 0; tm < 4; tm++) {
        #pragma unroll
        for (int tn = 0; tn < 3; tn++) {
            int col = bn + wn*48 + tn*16 + lcol;
            float bv = bias[col];
            int which = (col >= 1536) ? 2 : (col >= 768 ? 1 : 0);
            int cc = col - which * 768;
            int h = cc >> 6, d = cc & 63;
            int rowbase = bm + wm*64 + tm*16 + quad*4;
            int bb = rowbase >> 11, n0 = rowbase & 2047;
            int bh = bb * 12 + h;
            if (which == 2) {                 // V: tiled V^T store, dense window
                short4 s4;
                s4.x = f2bf(acc[tm][tn][0] + bv);
                s4.y = f2bf(acc[tm][tn][1] + bv);
                s4.z = f2bf(acc[tm][tn][2] + bv);
                s4.w = f2bf(acc[tm][tn][3] + bv);
                *(short4*)(Vt + (((size_t)bh*32 + (n0 >> 6))*64 + d)*64 + (n0 & 63)) = s4;
            } else {
                #pragma unroll
                for (int reg = 0; reg < 4; reg++) {
                    float v = acc[tm][tn][reg] + bv;
                    if (which == 0) v *= SCLQ;
                    short* dst = (which == 0) ? Qb : Kb;
                    dst[((size_t)bh*2048 + n0 + reg)*64 + d] = f2bf(v);
                }
            }
        }
    }
}

// ---------------------------------------------------------------------------
// Flash attention — byte-identical R11 (55.2us measured control).
// ---------------------------------------------------------------------------
__global__ __launch_bounds__(256)
void attn_k(const short* __restrict__ Q, const short* __restrict__ K,
            const short* __restrict__ Vt, short* __restrict__ Ab)
{
    __shared__ short Ks[2][4096];      // [kv][d] xor-swizzled chunks
    __shared__ short Vs[2][4096];      // [d][kv] xor-swizzled chunks
    __shared__ short Ps[64 * 72];      // shared P tile [q][kv], pad 72
    __shared__ float lsum[64];

    const int tid = threadIdx.x, lane = tid & 63, w = tid >> 6;
    const int quad = lane >> 4, lcol = lane & 15;
    const int bid = blockIdx.x;
    const int bh = bid % 24, qt = bid / 24;
    const int b = bh / 12, h = bh - b * 12;

    const short* Kg = K  + (size_t)bh * 131072;   // [n][d] rows, tile = 8KB
    const short* Vg = Vt + (size_t)bh * 131072;   // tiled [kt][d][n64], 8KB

    bf16x8 qf[4][2];
    {
        const short* Qg = Q + ((size_t)bh * 2048 + (size_t)qt * 64) * 64;
        #pragma unroll
        for (int qs = 0; qs < 4; qs++)
            #pragma unroll
            for (int ks = 0; ks < 2; ks++)
                qf[qs][ks] = *(const bf16x8*)(Qg + (qs*16 + lcol) * 64 + ks*32 + quad*8);
    }

    if (tid < 64) lsum[tid] = 0.f;
    #pragma unroll
    for (int i = 0; i < 2; i++) {
        int c = tid + i * 256, row = c >> 3, cs = c & 7, gc = cs ^ (row & 7);
        gl_lds16(Kg + row * 64 + gc * 8, Ks[0] + c * 8);
        gl_lds16(Vg + row * 64 + gc * 8, Vs[0] + c * 8);
    }
    __syncthreads();

    f32x4 o[4];
    #pragma unroll
    for (int tn = 0; tn < 4; tn++) o[tn] = (f32x4){0.f, 0.f, 0.f, 0.f};
    float lp[4] = {0.f, 0.f, 0.f, 0.f};

    const int krow = w * 16 + lcol;
    const int ksw  = krow & 7;

    for (int kt = 0; kt < 32; kt++) {
        const int p = kt & 1;
        if (kt < 31) {
            #pragma unroll
            for (int i = 0; i < 2; i++) {
                int c = tid + i * 256, row = c >> 3, cs = c & 7, gc = cs ^ (row & 7);
                gl_lds16(Kg + (kt + 1) * 4096 + row * 64 + gc * 8, Ks[p ^ 1] + c * 8);
                gl_lds16(Vg + (kt + 1) * 4096 + row * 64 + gc * 8, Vs[p ^ 1] + c * 8);
            }
        }

        f32x4 st[4];
        #pragma unroll
        for (int qs = 0; qs < 4; qs++) st[qs] = (f32x4){0.f, 0.f, 0.f, 0.f};
        #pragma unroll
        for (int ks = 0; ks < 2; ks++) {
            bf16x8 kf = *(const bf16x8*)(Ks[p] + krow * 64 + (((ks*4 + quad) ^ ksw) << 3));
            #pragma unroll
            for (int qs = 0; qs < 4; qs++)
                st[qs] = __builtin_amdgcn_mfma_f32_16x16x32_bf16(kf, qf[qs][ks], st[qs], 0, 0, 0);
        }

        #pragma unroll
        for (int qs = 0; qs < 4; qs++) {
            float p0 = exp2fast(st[qs][0]), p1 = exp2fast(st[qs][1]);
            float p2 = exp2fast(st[qs][2]), p3 = exp2fast(st[qs][3]);
            lp[qs] += (p0 + p1) + (p2 + p3);
            uint32_t uu[2] = { packbf(p0, p1), packbf(p2, p3) };
            *(uint32_t*)(Ps + (qs*16 + lcol) * 72 + w*16 + quad*4)     = uu[0];
            *(uint32_t*)(Ps + (qs*16 + lcol) * 72 + w*16 + quad*4 + 2) = uu[1];
        }
        __syncthreads();               // barrier 1: P visible + prefetch drained

        #pragma unroll
        for (int ks = 0; ks < 2; ks++) {
            bf16x8 ap = *(const bf16x8*)(Ps + (w*16 + lcol) * 72 + ks * 32 + quad * 8);
            #pragma unroll
            for (int tn = 0; tn < 4; tn++) {
                int row = tn * 16 + lcol;
                bf16x8 bv = *(const bf16x8*)(Vs[p] + row * 64 +
                                             (((ks * 4 + quad) ^ (row & 7)) << 3));
                o[tn] = __builtin_amdgcn_mfma_f32_16x16x32_bf16(ap, bv, o[tn], 0, 0, 0);
            }
        }
        __syncthreads();               // barrier 2: staging swap + Ps reuse
    }

    #pragma unroll
    for (int qs = 0; qs < 4; qs++) {
        float v = lp[qs];
        v += __shfl_xor(v, 16, 64);
        v += __shfl_xor(v, 32, 64);
        if (quad == 0) atomicAdd(&lsum[qs*16 + lcol], v);
    }
    __syncthreads();
    #pragma unroll
    for (int tn = 0; tn < 4; tn++) {
        #pragma unroll
        for (int r = 0; r < 4; r++) {
            int q = qt * 64 + w * 16 + quad * 4 + r;
            int d = h * 64 + tn * 16 + lcol;
            float rl = 1.0f / lsum[w * 16 + quad * 4 + r];
            Ab[((size_t)(b * 2048 + q)) * 768 + d] = f2bf(o[tn][r] * rl);
        }
    }
}

// ---------------------------------------------------------------------------
// out-proj GEMM R13: 64x96 tiles, 512 blocks = 2/CU, double-buffered DMA.
// ---------------------------------------------------------------------------
__global__ __launch_bounds__(256)
void gemm_out(const short* __restrict__ A, const short* __restrict__ Bt,
              const float* __restrict__ bias, float* __restrict__ Of)
{
    __shared__ short As[2][64 * 32];   // 256 chunks each buffer
    __shared__ short Bs[2][96 * 32];   // 384 chunks
    const int tid = threadIdx.x, lane = tid & 63, w = tid >> 6;
    const int wm = w >> 1, wn = w & 1, quad = lane >> 4, lcol = lane & 15;
    const int bm = blockIdx.y * 64, bn = blockIdx.x * 96;

    f32x4 acc[2][3];
    #pragma unroll
    for (int i = 0; i < 2; i++)
        #pragma unroll
        for (int j = 0; j < 3; j++) acc[i][j] = (f32x4){0.f, 0.f, 0.f, 0.f};

    {
        int row = tid >> 2, cs = tid & 3;
        gl_lds16(A  + (size_t)(bm + row) * 768 + cs * 8, As[0] + tid * 8);
        gl_lds16(Bt + (size_t)(bn + row) * 768 + cs * 8, Bs[0] + tid * 8);
        if (tid < 128) {
            int c = 256 + tid, row2 = c >> 2, cs2 = c & 3;
            gl_lds16(Bt + (size_t)(bn + row2) * 768 + cs2 * 8, Bs[0] + c * 8);
        }
    }
    __syncthreads();

    for (int it = 0; it < 24; it++) {
        const int p = it & 1;
        if (it < 23) {
            int kt = (it + 1) * 32;
            int row = tid >> 2, cs = tid & 3;
            gl_lds16(A  + (size_t)(bm + row) * 768 + kt + cs * 8, As[p ^ 1] + tid * 8);
            gl_lds16(Bt + (size_t)(bn + row) * 768 + kt + cs * 8, Bs[p ^ 1] + tid * 8);
            if (tid < 128) {
                int c = 256 + tid, row2 = c >> 2, cs2 = c & 3;
                gl_lds16(Bt + (size_t)(bn + row2) * 768 + kt + cs2 * 8, Bs[p ^ 1] + c * 8);
            }
        }
        bf16x8 a[2], b[3];
        #pragma unroll
        for (int tm = 0; tm < 2; tm++)
            a[tm] = *(const bf16x8*)(As[p] + (wm*32 + tm*16 + lcol) * 32 + quad * 8);
        #pragma unroll
        for (int tn = 0; tn < 3; tn++)
            b[tn] = *(const bf16x8*)(Bs[p] + (wn*48 + tn*16 + lcol) * 32 + quad * 8);
        #pragma unroll
        for (int tm = 0; tm < 2; tm++)
            #pragma unroll
            for (int tn = 0; tn < 3; tn++)
                acc[tm][tn] = __builtin_amdgcn_mfma_f32_16x16x32_bf16(a[tm], b[tn], acc[tm][tn], 0, 0, 0);
        __syncthreads();
    }
    #pragma unroll
    for (int tm = 0; tm < 2; tm++) {
        #pragma unroll
        for (int tn = 0; tn < 3; tn++) {
            int col = bn + wn*48 + tn*16 + lcol;
            float bv = bias[col];
            #pragma unroll
            for (int reg = 0; reg < 4; reg++) {
                int row = bm + wm*32 + tm*16 + quad*4 + reg;
                Of[(size_t)row * 768 + col] = acc[tm][tn][reg] + bv;
            }
        }
    }
}

// ---------------------------------------------------------------------------
extern "C" void kernel_launch(void* const* d_in, const int* in_sizes, int n_in,
                              void* d_out, int out_size, void* d_ws, size_t ws_size,
                              hipStream_t stream)
{
    (void)in_sizes; (void)n_in; (void)out_size;
    const float* x     = (const float*)d_in[0];
    const float* w_qkv = (const float*)d_in[1];
    const float* b_qkv = (const float*)d_in[2];
    const float* w_out = (const float*)d_in[3];
    const float* b_out = (const float*)d_in[4];
    float* out = (float*)d_out;

    const size_t XSZ = (size_t)4096 * 768;
    const size_t WQ  = (size_t)2304 * 768;
    const size_t WO  = (size_t)768 * 768;
    const size_t HSZ = (size_t)24 * 2048 * 64;
    short* Xb  = (short*)d_ws;
    short* Wqt = Xb + XSZ;
    short* Qb  = Wqt + WQ;
    short* Kb  = Qb + HSZ;
    short* Vt  = Kb + HSZ;
    short* Ab  = Xb;                       // x dead after gemm_qkv

    const bool sepWot = ws_size >= (XSZ + WQ + 3*HSZ + WO) * sizeof(short);
    short* Wot = sepWot ? (Vt + HSZ) : Wqt;   // else alias (w_qkv^T dead after gemm0)

    if (sepWot) {
        prep_k<<<2112, 256, 0, stream>>>(x, Xb, w_qkv, Wqt, w_out, Wot);
        gemm_qkv<<<dim3(24, 32), 256, 0, stream>>>(Xb, Wqt, b_qkv, Qb, Kb, Vt);
    } else {
        prep_k<<<1968, 256, 0, stream>>>(x, Xb, w_qkv, Wqt, w_out, Wot);
        gemm_qkv<<<dim3(24, 32), 256, 0, stream>>>(Xb, Wqt, b_qkv, Qb, Kb, Vt);
        tr_w<<<dim3(12, 12), 256, 0, stream>>>(w_out, Wot, 768, 768);
    }
    attn_k<<<768, 256, 0, stream>>>(Qb, Kb, Vt, Ab);
    gemm_out<<<dim3(8, 64), 256, 0, stream>>>(Ab, Wot, b_out, out);
}